// Round 1
// baseline (320.335 us; speedup 1.0000x reference)
//
#include <hip/hip_runtime.h>
#include <cstdint>

#define B_  64
#define P_  196
#define C_  768
#define HS_ 384
#define M_  49152

// K-chunk = 16 scalars -> 8 rbf tiles (k16) + 1 silu tile per chunk.
// fc1: 13 chunks (12 full + tail{2 rbf,1 silu}) => KT1 = 111 tiles
// fc2: 24 chunks => KT2 = 216 tiles
#define NC1 13
#define KT1 111
#define NT1 12
#define NC2 24
#define KT2 216
#define NT2 7

#define H1_ELEMS  ((size_t)M_ * HS_)
#define W1P_ELEMS ((size_t)KT1 * NT1 * 512) // 681,984
#define W2P_ELEMS ((size_t)KT2 * NT2 * 512) // 774,144

typedef __attribute__((ext_vector_type(8)))  short short8;
typedef __attribute__((ext_vector_type(16))) float f32x16;

#define MFMA(w, a, c) __builtin_amdgcn_mfma_f32_32x32x16_bf16((w), (a), (c), 0, 0, 0)

static __device__ __forceinline__ float bf2f(unsigned short u) {
    union { unsigned int i; float f; } v; v.i = ((unsigned int)u) << 16; return v.f;
}
static __device__ __forceinline__ unsigned short f2bf_rne(float f) {
    union { float f; unsigned int i; } v; v.f = f;
    unsigned int r = v.i + 0x7FFFu + ((v.i >> 16) & 1u);
    return (unsigned short)(r >> 16);
}
static __device__ __forceinline__ unsigned int pack2(float a, float b) {
    unsigned int ua = __float_as_uint(a) + 0x8000u;
    unsigned int ub = __float_as_uint(b) + 0x8000u;
    return __builtin_amdgcn_perm(ub, ua, 0x07060302u);  // [a | b] (a = low ushort)
}
// 8 RBF basis of one scalar: exp(-((s-g_j)*3.5)^2), g_j = -1 + j*2/7
static __device__ __forceinline__ short8 rbf8(float s) {
    float t0 = 3.5f * s + 3.5f;               // d_j = t0 - j
    union { short8 s8; unsigned int u[4]; } r;
#pragma unroll
    for (int q = 0; q < 4; q++) {
        float d0 = t0 - (float)(2 * q);
        float d1 = t0 - (float)(2 * q + 1);
        r.u[q] = pack2(__expf(-d0 * d0), __expf(-d1 * d1));
    }
    return r.s8;
}
static __device__ __forceinline__ unsigned int silu2(float a, float b) {
    float fa = a * __builtin_amdgcn_rcpf(1.f + __expf(-a));
    float fb = b * __builtin_amdgcn_rcpf(1.f + __expf(-b));
    return pack2(fa, fb);
}

// Weights packed as A-operand frags in consumption order (unchanged layout):
// w[tt][nt][lane][j] = W[n = nt*32+(lane&31)][k_logical(tt, khalf=lane>>5, j)]
__global__ void pack_w_kernel(const float* __restrict__ w1s,
                              const float* __restrict__ w1b,
                              const float* __restrict__ w2s,
                              const float* __restrict__ w2b,
                              unsigned short* __restrict__ w1p,
                              unsigned short* __restrict__ w2p) {
    size_t idx = (size_t)blockIdx.x * 256 + threadIdx.x;
    if (idx < W1P_ELEMS) {
        int j    = idx & 7;
        int lane = (idx >> 3) & 63;
        int lin  = idx >> 9;             // tt*NT1 + nt
        int nt   = lin % NT1;
        int tt   = lin / NT1;
        int cc   = (tt < 108) ? tt / 9 : 12;
        int kk   = (tt < 108) ? tt % 9 : (tt - 108);
        int ktl  = (cc < 12) ? kk : ((kk < 2) ? kk : 8);
        int n = nt * 32 + (lane & 31);
        int khalf = lane >> 5;
        float v = 0.f;
        if (ktl < 8) {
            int p = cc * 16 + ktl * 2 + khalf;
            if (p < P_) v = w1s[(size_t)n * 1568 + p * 8 + j];
        } else {
            int p = cc * 16 + khalf * 8 + j;
            if (p < P_) v = w1b[(size_t)n * 196 + p];
        }
        w1p[idx] = f2bf_rne(v);
    } else {
        size_t idx2 = idx - W1P_ELEMS;
        if (idx2 < W2P_ELEMS) {
            int j    = idx2 & 7;
            int lane = (idx2 >> 3) & 63;
            int lin  = idx2 >> 9;        // tt*NT2 + nt
            int nt   = lin % NT2;
            int tt   = lin / NT2;
            int cc   = tt / 9;
            int ktl  = tt % 9;
            int n = nt * 32 + (lane & 31);
            int khalf = lane >> 5;
            float v = 0.f;
            if (n < P_) {
                if (ktl < 8) {
                    int s = cc * 16 + ktl * 2 + khalf;
                    v = w2s[(size_t)n * 3072 + s * 8 + j];
                } else {
                    int s = cc * 16 + khalf * 8 + j;
                    v = w2b[(size_t)n * 384 + s];
                }
            }
            w2p[idx2] = f2bf_rne(v);
        }
    }
}

// frag LDS: [buf 2][tile 9][rt 2][lane 64 * 8] ushort; FB_ = 9216 ushort/buf.
#define FB_  9216

// 8-wave structure: wave = sg = tid>>6; rt = sg>>2 (row half), ntg = sg&3.
// Each wave owns 1 rt x {3 nt (fc1) | 2 nt (fc2)} -> acc 48/32 regs, fits
// 128-reg cap -> 2 blocks/CU = 4 waves/SIMD (was 2).

// fc1: D[n][r] = W1 * act(x)^T; writes h1t[n][r].
__global__ __launch_bounds__(512, 4)
void fc1_kernel(const float* __restrict__ x,
                const unsigned short* __restrict__ w1p,
                const float* __restrict__ b1,
                unsigned short* __restrict__ h1t) {
    __shared__ __align__(16) unsigned short frag[2 * FB_];
    int blk = blockIdx.x;
    int tid = threadIdx.x;
    int b   = blk / 12;
    int c0  = (blk % 12) * 64;
    const float* xb = x + (size_t)b * (P_ * C_);

    int pr  = tid & 63;
    int sg  = tid >> 6;                       // 0..7
    int prt = pr >> 5, pl31 = pr & 31;
    int pbase_rbf  = (prt << 9) + pl31 * 8;
    int pbase_silu = 8 * 1024 + (prt << 9) + (((sg >> 2) << 5) | pl31) * 8 + (sg & 3) * 2;

    int lane = tid & 63;
    int l31 = lane & 31, half = lane >> 5;
    int rt  = sg >> 2;
    int nt0 = (sg & 3) * 3;
    int abase = rt * 512 + lane * 8;          // this wave's rt-half of each tile

    f32x16 acc[3];
#pragma unroll
    for (int nt = 0; nt < 3; nt++)
#pragma unroll
        for (int i = 0; i < 16; i++) acc[nt][i] = 0.f;

    const short8* wp = (const short8*)w1p;
    short8 wbuf[3][3];

    auto wload = [&](int d, const short8* wt0, int kk) {
        const short8* wt = wt0 + (size_t)kk * (NT1 * 64);
        wbuf[d][0] = wt[0]; wbuf[d][1] = wt[64]; wbuf[d][2] = wt[128];
    };
    auto produce = [&](int fb, const float (&rb)[2]) {
#pragma unroll
        for (int i = 0; i < 2; i++) {
            int sl = sg * 2 + i;
            *(short8*)&frag[fb + (sl >> 1) * 1024 + ((sl & 1) << 8) + pbase_rbf] = rbf8(rb[i]);
        }
        *(unsigned int*)&frag[fb + pbase_silu] = silu2(rb[0], rb[1]);
    };
    auto do_mfma = [&](short8 w0, short8 w1, short8 w2, short8 a0) {
        acc[0] = MFMA(w0, a0, acc[0]);
        acc[1] = MFMA(w1, a0, acc[1]);
        acc[2] = MFMA(w2, a0, acc[2]);
    };
    auto consume = [&](int fb, const short8* wt0) {
        const unsigned short* fg = &frag[fb];
        short8 a0 = *(const short8*)&fg[abase];
#pragma unroll
        for (int kk = 0; kk < 9; kk++) {
            short8 na0;
            if (kk < 8) na0 = *(const short8*)&fg[(kk + 1) * 1024 + abase];
            short8 w0 = wbuf[kk % 3][0], w1 = wbuf[kk % 3][1], w2 = wbuf[kk % 3][2];
            if (kk < 6) wload(kk % 3, wt0, kk + 3);
            do_mfma(w0, w1, w2, a0);
            if (kk < 8) a0 = na0;
        }
    };
    // body(cc): [post-barrier] raw loads cc+2 -> rbL; weight preload chunk cc;
    //           produce cc+1 from rbP; consume cc; barrier.
    auto body = [&](int cc, const float (&rbP)[2], float (&rbL)[2]) {
#pragma unroll
        for (int i = 0; i < 2; i++) {
            int p = (cc + 2) * 16 + sg * 2 + i;
            p = (p < P_) ? p : (P_ - 1);
            rbL[i] = xb[(size_t)p * C_ + c0 + pr];
        }
        const short8* wt0 = wp + ((size_t)(cc * 9) * NT1 + nt0) * 64 + lane;
        wload(0, wt0, 0); wload(1, wt0, 1); wload(2, wt0, 2);
        produce(((cc + 1) & 1) * FB_, rbP);
        consume((cc & 1) * FB_, wt0);
        __syncthreads();
    };

    float rbA[2], rbB[2];
#pragma unroll
    for (int i = 0; i < 2; i++) {
        rbA[i] = xb[(size_t)(sg * 2 + i) * C_ + c0 + pr];
        rbB[i] = xb[(size_t)(16 + sg * 2 + i) * C_ + c0 + pr];
    }
    produce(0, rbA);            // chunk 0 -> frag[0]
    __syncthreads();

    for (int c2 = 0; c2 < 6; c2++) {          // chunks 0..11
        body(2 * c2,     rbB, rbA);           // produce cc+1 (odd) from rbB
        body(2 * c2 + 1, rbA, rbB);
    }
    // tail: consume chunk 12 (tiles ktl {0,1,8}; weights linear 108..110)
    {
        const short8* wt0 = wp + ((size_t)108 * NT1 + nt0) * 64 + lane;
        wload(0, wt0, 0); wload(1, wt0, 1); wload(2, wt0, 2);
        const unsigned short* fg = &frag[0];  // chunk 12 parity 0
#pragma unroll
        for (int kk = 0; kk < 3; kk++) {
            int ktl = (kk < 2) ? kk : 8;
            short8 a0 = *(const short8*)&fg[ktl * 1024 + abase];
            do_mfma(wbuf[kk][0], wbuf[kk][1], wbuf[kk][2], a0);
        }
    }

    // epilogue: h1t[n][r]
#pragma unroll
    for (int nt = 0; nt < 3; nt++) {
        int n0 = (nt0 + nt) * 32 + 4 * half;
#pragma unroll
        for (int reg = 0; reg < 16; reg++) {
            int n = n0 + (reg & 3) + 8 * (reg >> 2);
            float bv = b1[n];
            h1t[(size_t)n * M_ + blk * 64 + rt * 32 + l31] = f2bf_rne(acc[nt][reg] + bv);
        }
    }
}

// fc2: D[p][r] = W2 * act(h1)^T; out = D + b2 + x.
__global__ __launch_bounds__(512, 4)
void fc2_kernel(const unsigned short* __restrict__ h1t,
                const unsigned short* __restrict__ w2p,
                const float* __restrict__ b2,
                const float* __restrict__ x,
                float* __restrict__ out) {
    __shared__ __align__(16) unsigned short frag[2 * FB_];
    int blk = blockIdx.x;
    int tid = threadIdx.x;
    int rbase = blk * 64;

    int pr  = tid & 63;
    int sg  = tid >> 6;
    int prt = pr >> 5, pl31 = pr & 31;
    int pbase_rbf  = (prt << 9) + pl31 * 8;
    int pbase_silu = 8 * 1024 + (prt << 9) + (((sg >> 2) << 5) | pl31) * 8 + (sg & 3) * 2;

    int lane = tid & 63;
    int l31 = lane & 31, half = lane >> 5;
    int rt  = sg >> 2;
    int ntg = sg & 3;
    int nt0 = ntg * 2;
    bool two = (ntg < 3);                     // ntg 3 owns only 1 real tile
    int off1 = two ? 64 : 0;
    int abase = rt * 512 + lane * 8;

    f32x16 acc[2];
#pragma unroll
    for (int nt = 0; nt < 2; nt++)
#pragma unroll
        for (int i = 0; i < 16; i++) acc[nt][i] = 0.f;

    const short8* wp = (const short8*)w2p;
    short8 wbuf[3][2];

    auto wload = [&](int d, const short8* wt0, int kk) {
        const short8* wt = wt0 + (size_t)kk * (NT2 * 64);
        wbuf[d][0] = wt[0]; wbuf[d][1] = wt[off1];
    };
    auto produce = [&](int fb, const unsigned short (&rb)[2]) {
        float v0 = bf2f(rb[0]), v1 = bf2f(rb[1]);
        float vv[2] = {v0, v1};
#pragma unroll
        for (int i = 0; i < 2; i++) {
            int sl = sg * 2 + i;
            *(short8*)&frag[fb + (sl >> 1) * 1024 + ((sl & 1) << 8) + pbase_rbf] = rbf8(vv[i]);
        }
        *(unsigned int*)&frag[fb + pbase_silu] = silu2(v0, v1);
    };
    auto do_mfma = [&](short8 w0, short8 w1, short8 a0) {
        acc[0] = MFMA(w0, a0, acc[0]);
        if (two) acc[1] = MFMA(w1, a0, acc[1]);
    };
    auto consume = [&](int fb, const short8* wt0) {
        const unsigned short* fg = &frag[fb];
        short8 a0 = *(const short8*)&fg[abase];
#pragma unroll
        for (int kk = 0; kk < 9; kk++) {
            short8 na0;
            if (kk < 8) na0 = *(const short8*)&fg[(kk + 1) * 1024 + abase];
            short8 w0 = wbuf[kk % 3][0], w1 = wbuf[kk % 3][1];
            if (kk < 6) wload(kk % 3, wt0, kk + 3);
            do_mfma(w0, w1, a0);
            if (kk < 8) a0 = na0;
        }
    };
    auto body = [&](int cc, const unsigned short (&rbP)[2], unsigned short (&rbL)[2]) {
#pragma unroll
        for (int i = 0; i < 2; i++) {
            int s = (cc + 2) * 16 + sg * 2 + i;
            s = (s < HS_) ? s : (HS_ - 1);
            rbL[i] = h1t[(size_t)s * M_ + rbase + pr];
        }
        const short8* wt0 = wp + ((size_t)(cc * 9) * NT2 + nt0) * 64 + lane;
        wload(0, wt0, 0); wload(1, wt0, 1); wload(2, wt0, 2);
        if (cc + 1 < NC2) produce(((cc + 1) & 1) * FB_, rbP);
        consume((cc & 1) * FB_, wt0);
        __syncthreads();
    };

    unsigned short rbA[2], rbB[2];
#pragma unroll
    for (int i = 0; i < 2; i++) {
        rbA[i] = h1t[(size_t)(sg * 2 + i) * M_ + rbase + pr];
        rbB[i] = h1t[(size_t)(16 + sg * 2 + i) * M_ + rbase + pr];
    }
    produce(0, rbA);            // chunk 0 -> frag[0]
    __syncthreads();

    for (int c2 = 0; c2 < 12; c2++) {        // chunks 0..23
        body(2 * c2,     rbB, rbA);
        body(2 * c2 + 1, rbA, rbB);
    }

    // epilogue: out[b,p,c] = acc + b2[p] + x[b,p,c]
    int b = blk / 12;
    int c0 = (blk % 12) * 64;
#pragma unroll
    for (int nt = 0; nt < 2; nt++) {
        if (nt == 0 || two) {
            int p0 = (nt0 + nt) * 32 + 4 * half;
#pragma unroll
            for (int reg = 0; reg < 16; reg++) {
                int p = p0 + (reg & 3) + 8 * (reg >> 2);
                if (p < P_) {
                    float bv = b2[p];
                    size_t off = ((size_t)b * P_ + p) * C_ + c0 + rt * 32 + l31;
                    out[off] = acc[nt][reg] + bv + x[off];
                }
            }
        }
    }
}

extern "C" void kernel_launch(void* const* d_in, const int* in_sizes, int n_in,
                              void* d_out, int out_size, void* d_ws, size_t ws_size,
                              hipStream_t stream) {
    const float* x   = (const float*)d_in[0];
    const float* w1s = (const float*)d_in[1];
    const float* w1b = (const float*)d_in[2];
    const float* b1  = (const float*)d_in[3];
    const float* w2s = (const float*)d_in[4];
    const float* w2b = (const float*)d_in[5];
    const float* b2  = (const float*)d_in[6];
    float* out = (float*)d_out;

    unsigned short* h1t = (unsigned short*)d_ws;            // 37.75 MB bf16 [n][r]
    unsigned short* w1p = h1t + H1_ELEMS;
    unsigned short* w2p = w1p + W1P_ELEMS;                  // total ~40.7 MB

    int pack_blocks = (int)((W1P_ELEMS + W2P_ELEMS) / 256);
    pack_w_kernel<<<pack_blocks, 256, 0, stream>>>(w1s, w1b, w2s, w2b, w1p, w2p);
    fc1_kernel<<<M_ / 64, 512, 0, stream>>>(x, w1p, b1, h1t);
    fc2_kernel<<<M_ / 64, 512, 0, stream>>>(h1t, w2p, b2, x, out);
}

// Round 2
// 278.690 us; speedup vs baseline: 1.1494x; 1.1494x over previous
//
#include <hip/hip_runtime.h>
#include <cstdint>

#define B_  64
#define P_  196
#define C_  768
#define HS_ 384
#define M_  49152

// K-chunk = 16 scalars -> 8 rbf tiles (k16) + 1 silu tile per chunk.
// fc1: 13 chunks (12 full + tail{2 rbf,1 silu}) => KT1 = 111 tiles
// fc2: 24 chunks => KT2 = 216 tiles
#define NC1 13
#define KT1 111
#define NT1 12
#define NC2 24
#define KT2 216
#define NT2 7

#define H1_ELEMS  ((size_t)M_ * HS_)
#define W1P_ELEMS ((size_t)KT1 * NT1 * 512) // 681,984
#define W2P_ELEMS ((size_t)KT2 * NT2 * 512) // 774,144

typedef __attribute__((ext_vector_type(8)))  short short8;
typedef __attribute__((ext_vector_type(16))) float f32x16;

#define MFMA(w, a, c) __builtin_amdgcn_mfma_f32_32x32x16_bf16((w), (a), (c), 0, 0, 0)

static __device__ __forceinline__ float bf2f(unsigned short u) {
    union { unsigned int i; float f; } v; v.i = ((unsigned int)u) << 16; return v.f;
}
static __device__ __forceinline__ unsigned short f2bf_rne(float f) {
    union { float f; unsigned int i; } v; v.f = f;
    unsigned int r = v.i + 0x7FFFu + ((v.i >> 16) & 1u);
    return (unsigned short)(r >> 16);
}
static __device__ __forceinline__ unsigned int pack2(float a, float b) {
    unsigned int ua = __float_as_uint(a) + 0x8000u;
    unsigned int ub = __float_as_uint(b) + 0x8000u;
    return __builtin_amdgcn_perm(ub, ua, 0x07060302u);  // [a | b] (a = low ushort)
}
// 8 RBF basis: exp(-(3.5s+3.5-j)^2) = exp2(-(u_j)^2), u_j = A*s+A - j*R,
// R = sqrt(log2 e). Per basis: 1 sub + 1 neg-mul + 1 v_exp (fma form).
static __device__ __forceinline__ short8 rbf8(float s) {
    const float Rr = 1.2011224087864498f;     // sqrt(log2 e)
    const float Aa = 4.2039284307525743f;     // 3.5 * Rr
    float t1 = __builtin_fmaf(Aa, s, Aa);
    union { short8 s8; unsigned int u[4]; } r;
#pragma unroll
    for (int q = 0; q < 4; q++) {
        float u0 = t1 - (float)(2 * q) * Rr;
        float u1 = t1 - (float)(2 * q + 1) * Rr;
        r.u[q] = pack2(__builtin_amdgcn_exp2f(-u0 * u0),
                       __builtin_amdgcn_exp2f(-u1 * u1));
    }
    return r.s8;
}
static __device__ __forceinline__ unsigned int silu2(float a, float b) {
    const float L2E = 1.4426950408889634f;
    float fa = a * __builtin_amdgcn_rcpf(1.f + __builtin_amdgcn_exp2f(-L2E * a));
    float fb = b * __builtin_amdgcn_rcpf(1.f + __builtin_amdgcn_exp2f(-L2E * b));
    return pack2(fa, fb);
}

// Weights packed as A-operand frags in consumption order (unchanged):
// w[tt][nt][lane][j] = W[n = nt*32+(lane&31)][k_logical(tt, khalf=lane>>5, j)]
__global__ void pack_w_kernel(const float* __restrict__ w1s,
                              const float* __restrict__ w1b,
                              const float* __restrict__ w2s,
                              const float* __restrict__ w2b,
                              unsigned short* __restrict__ w1p,
                              unsigned short* __restrict__ w2p) {
    size_t idx = (size_t)blockIdx.x * 256 + threadIdx.x;
    if (idx < W1P_ELEMS) {
        int j    = idx & 7;
        int lane = (idx >> 3) & 63;
        int lin  = idx >> 9;             // tt*NT1 + nt
        int nt   = lin % NT1;
        int tt   = lin / NT1;
        int cc   = (tt < 108) ? tt / 9 : 12;
        int kk   = (tt < 108) ? tt % 9 : (tt - 108);
        int ktl  = (cc < 12) ? kk : ((kk < 2) ? kk : 8);
        int n = nt * 32 + (lane & 31);
        int khalf = lane >> 5;
        float v = 0.f;
        if (ktl < 8) {
            int p = cc * 16 + ktl * 2 + khalf;
            if (p < P_) v = w1s[(size_t)n * 1568 + p * 8 + j];
        } else {
            int p = cc * 16 + khalf * 8 + j;
            if (p < P_) v = w1b[(size_t)n * 196 + p];
        }
        w1p[idx] = f2bf_rne(v);
    } else {
        size_t idx2 = idx - W1P_ELEMS;
        if (idx2 < W2P_ELEMS) {
            int j    = idx2 & 7;
            int lane = (idx2 >> 3) & 63;
            int lin  = idx2 >> 9;        // tt*NT2 + nt
            int nt   = lin % NT2;
            int tt   = lin / NT2;
            int cc   = tt / 9;
            int ktl  = tt % 9;
            int n = nt * 32 + (lane & 31);
            int khalf = lane >> 5;
            float v = 0.f;
            if (n < P_) {
                if (ktl < 8) {
                    int s = cc * 16 + ktl * 2 + khalf;
                    v = w2s[(size_t)n * 3072 + s * 8 + j];
                } else {
                    int s = cc * 16 + khalf * 8 + j;
                    v = w2b[(size_t)n * 384 + s];
                }
            }
            w2p[idx2] = f2bf_rne(v);
        }
    }
}

// frag LDS: [buf 2][tile 9][rt 2][lane 64 * 8] ushort; FB_ = 9216 ushort/buf.
#define FB_  9216

// R2 structure: back to 4 waves / 2 rt per wave (restores 2x weight reuse
// per L2 load), with produce SLICES interleaved into the MFMA kk-loop so
// trans/VALU and MFMA pipes are fed concurrently within each wave.
// rbL global loads issued at kk>=5 (youngest in vmem queue -> never block
// the weight-load vmcnt waits).

// fc1: D[n][r] = W1 * act(x)^T; writes h1t[n][r].
__global__ __launch_bounds__(256, 2)
void fc1_kernel(const float* __restrict__ x,
                const unsigned short* __restrict__ w1p,
                const float* __restrict__ b1,
                unsigned short* __restrict__ h1t) {
    __shared__ __align__(16) unsigned short frag[2 * FB_];
    int blk = blockIdx.x;
    int tid = threadIdx.x;
    int b   = blk / 12;
    int c0  = (blk % 12) * 64;
    const float* xb = x + (size_t)b * (P_ * C_);

    int pr  = tid & 63;
    int sg  = tid >> 6;
    int prt = pr >> 5, pl31 = pr & 31;
    int pbase_rbf  = (prt << 9) + pl31 * 8;
    int pbase_silu = 8 * 1024 + (prt << 9) + (((sg >> 1) << 5) | pl31) * 8 + (sg & 1) * 4;

    int wave = sg, lane = tid & 63;
    int l31 = lane & 31, half = lane >> 5;
    int nt0 = wave * 3;

    f32x16 acc[2][3];
#pragma unroll
    for (int rt = 0; rt < 2; rt++)
#pragma unroll
        for (int nt = 0; nt < 3; nt++)
#pragma unroll
            for (int i = 0; i < 16; i++) acc[rt][nt][i] = 0.f;

    const short8* wp = (const short8*)w1p;
    short8 wbuf[3][3];

    auto wload = [&](int d, const short8* wt0, int kk) {
        const short8* wt = wt0 + (size_t)kk * (NT1 * 64);
        wbuf[d][0] = wt[0]; wbuf[d][1] = wt[64]; wbuf[d][2] = wt[128];
    };
    auto produce = [&](int fb, const float (&rb)[4]) {
#pragma unroll
        for (int i = 0; i < 4; i++) {
            int sl = sg * 4 + i;
            *(short8*)&frag[fb + (sl >> 1) * 1024 + ((sl & 1) << 8) + pbase_rbf] = rbf8(rb[i]);
        }
        uint2 sv;
        sv.x = silu2(rb[0], rb[1]);
        sv.y = silu2(rb[2], rb[3]);
        *(uint2*)&frag[fb + pbase_silu] = sv;
    };
    auto do_mfma = [&](short8 w0, short8 w1, short8 w2, short8 a0, short8 a1) {
        acc[0][0] = MFMA(w0, a0, acc[0][0]); acc[1][0] = MFMA(w0, a1, acc[1][0]);
        acc[0][1] = MFMA(w1, a0, acc[0][1]); acc[1][1] = MFMA(w1, a1, acc[1][1]);
        acc[0][2] = MFMA(w2, a0, acc[0][2]); acc[1][2] = MFMA(w2, a1, acc[1][2]);
    };
    // body(cc): weights preload; then kk-loop with produce(cc+1) slices and
    // rbL(cc+2) global loads interleaved between the MFMA groups; barrier.
    auto body = [&](int cc, const float (&rbP)[4], float (&rbL)[4]) {
        const short8* wt0 = wp + ((size_t)(cc * 9) * NT1 + nt0) * 64 + lane;
        wload(0, wt0, 0); wload(1, wt0, 1); wload(2, wt0, 2);
        int fbP = ((cc + 1) & 1) * FB_;
        const unsigned short* fg = &frag[(cc & 1) * FB_];
        short8 a0 = *(const short8*)&fg[lane * 8];
        short8 a1 = *(const short8*)&fg[512 + lane * 8];
#pragma unroll
        for (int kk = 0; kk < 9; kk++) {
            short8 na0, na1;
            if (kk < 8) {
                na0 = *(const short8*)&fg[(kk + 1) * 1024 + lane * 8];
                na1 = *(const short8*)&fg[(kk + 1) * 1024 + 512 + lane * 8];
            }
            short8 w0 = wbuf[kk % 3][0], w1 = wbuf[kk % 3][1], w2 = wbuf[kk % 3][2];
            if (kk < 6) wload(kk % 3, wt0, kk + 3);
            if (kk < 4) {                 // produce slice: 1 rbf8 + 1 ds_write
                int sl = sg * 4 + kk;
                *(short8*)&frag[fbP + (sl >> 1) * 1024 + ((sl & 1) << 8) + pbase_rbf] = rbf8(rbP[kk]);
            } else if (kk == 4) {         // produce slice: silu tile
                uint2 sv;
                sv.x = silu2(rbP[0], rbP[1]);
                sv.y = silu2(rbP[2], rbP[3]);
                *(uint2*)&frag[fbP + pbase_silu] = sv;
            } else {                      // kk 5..8: one rbL global load each
                int i = kk - 5;
                int p = (cc + 2) * 16 + sg * 4 + i;
                p = (p < P_) ? p : (P_ - 1);
                rbL[i] = xb[(size_t)p * C_ + c0 + pr];
            }
            do_mfma(w0, w1, w2, a0, a1);
            if (kk < 8) { a0 = na0; a1 = na1; }
        }
        __syncthreads();
    };

    float rbA[4], rbB[4];
#pragma unroll
    for (int i = 0; i < 4; i++) {
        rbA[i] = xb[(size_t)(sg * 4 + i) * C_ + c0 + pr];
        rbB[i] = xb[(size_t)(16 + sg * 4 + i) * C_ + c0 + pr];
    }
    produce(0, rbA);            // chunk 0 -> frag[0]
    __syncthreads();

    for (int c2 = 0; c2 < 6; c2++) {          // chunks 0..11
        body(2 * c2,     rbB, rbA);           // produce cc+1 (odd) from rbB
        body(2 * c2 + 1, rbA, rbB);
    }
    // tail: consume chunk 12 (tiles ktl {0,1,8}; weights linear 108..110)
    {
        const short8* wt0 = wp + ((size_t)108 * NT1 + nt0) * 64 + lane;
        wload(0, wt0, 0); wload(1, wt0, 1); wload(2, wt0, 2);
        const unsigned short* fg = &frag[0];  // chunk 12 parity 0
#pragma unroll
        for (int kk = 0; kk < 3; kk++) {
            int ktl = (kk < 2) ? kk : 8;
            short8 a0 = *(const short8*)&fg[ktl * 1024 + lane * 8];
            short8 a1 = *(const short8*)&fg[ktl * 1024 + 512 + lane * 8];
            do_mfma(wbuf[kk][0], wbuf[kk][1], wbuf[kk][2], a0, a1);
        }
    }

    // epilogue: h1t[n][r]
#pragma unroll
    for (int nt = 0; nt < 3; nt++) {
        int n0 = (nt0 + nt) * 32 + 4 * half;
#pragma unroll
        for (int reg = 0; reg < 16; reg++) {
            int n = n0 + (reg & 3) + 8 * (reg >> 2);
            float bv = b1[n];
#pragma unroll
            for (int rt = 0; rt < 2; rt++) {
                h1t[(size_t)n * M_ + blk * 64 + rt * 32 + l31] = f2bf_rne(acc[rt][nt][reg] + bv);
            }
        }
    }
}

// fc2: D[p][r] = W2 * act(h1)^T; out = D + b2 + x.
__global__ __launch_bounds__(256, 2)
void fc2_kernel(const unsigned short* __restrict__ h1t,
                const unsigned short* __restrict__ w2p,
                const float* __restrict__ b2,
                const float* __restrict__ x,
                float* __restrict__ out) {
    __shared__ __align__(16) unsigned short frag[2 * FB_];
    int blk = blockIdx.x;
    int tid = threadIdx.x;
    int rbase = blk * 64;

    int pr  = tid & 63;
    int sg  = tid >> 6;
    int prt = pr >> 5, pl31 = pr & 31;
    int pbase_rbf  = (prt << 9) + pl31 * 8;
    int pbase_silu = 8 * 1024 + (prt << 9) + (((sg >> 1) << 5) | pl31) * 8 + (sg & 1) * 4;

    int wave = sg, lane = tid & 63;
    int l31 = lane & 31, half = lane >> 5;
    int nt0 = wave * 2;
    int ntn = (wave < 3) ? 2 : 1;
    int off1 = (ntn > 1) ? 64 : 0;           // wave 3 dups its tile (discarded)

    f32x16 acc[2][2];
#pragma unroll
    for (int rt = 0; rt < 2; rt++)
#pragma unroll
        for (int nt = 0; nt < 2; nt++)
#pragma unroll
            for (int i = 0; i < 16; i++) acc[rt][nt][i] = 0.f;

    const short8* wp = (const short8*)w2p;
    short8 wbuf[3][2];

    auto wload = [&](int d, const short8* wt0, int kk) {
        const short8* wt = wt0 + (size_t)kk * (NT2 * 64);
        wbuf[d][0] = wt[0]; wbuf[d][1] = wt[off1];
    };
    auto produce = [&](int fb, const unsigned short (&rb)[4]) {
        float v0 = bf2f(rb[0]), v1 = bf2f(rb[1]), v2 = bf2f(rb[2]), v3 = bf2f(rb[3]);
        float vv[4] = {v0, v1, v2, v3};
#pragma unroll
        for (int i = 0; i < 4; i++) {
            int sl = sg * 4 + i;
            *(short8*)&frag[fb + (sl >> 1) * 1024 + ((sl & 1) << 8) + pbase_rbf] = rbf8(vv[i]);
        }
        uint2 sv;
        sv.x = silu2(v0, v1);
        sv.y = silu2(v2, v3);
        *(uint2*)&frag[fb + pbase_silu] = sv;
    };
    auto do_mfma = [&](short8 w0, short8 w1, short8 a0, short8 a1) {
        acc[0][0] = MFMA(w0, a0, acc[0][0]); acc[1][0] = MFMA(w0, a1, acc[1][0]);
        if (ntn == 2) {
            acc[0][1] = MFMA(w1, a0, acc[0][1]); acc[1][1] = MFMA(w1, a1, acc[1][1]);
        }
    };
    auto body = [&](int cc, const unsigned short (&rbP)[4], unsigned short (&rbL)[4]) {
        bool doProd = (cc + 1 < NC2);
        const short8* wt0 = wp + ((size_t)(cc * 9) * NT2 + nt0) * 64 + lane;
        wload(0, wt0, 0); wload(1, wt0, 1); wload(2, wt0, 2);
        int fbP = ((cc + 1) & 1) * FB_;
        const unsigned short* fg = &frag[(cc & 1) * FB_];
        short8 a0 = *(const short8*)&fg[lane * 8];
        short8 a1 = *(const short8*)&fg[512 + lane * 8];
#pragma unroll
        for (int kk = 0; kk < 9; kk++) {
            short8 na0, na1;
            if (kk < 8) {
                na0 = *(const short8*)&fg[(kk + 1) * 1024 + lane * 8];
                na1 = *(const short8*)&fg[(kk + 1) * 1024 + 512 + lane * 8];
            }
            short8 w0 = wbuf[kk % 3][0], w1 = wbuf[kk % 3][1];
            if (kk < 6) wload(kk % 3, wt0, kk + 3);
            if (kk < 4) {
                if (doProd) {
                    int sl = sg * 4 + kk;
                    *(short8*)&frag[fbP + (sl >> 1) * 1024 + ((sl & 1) << 8) + pbase_rbf] =
                        rbf8(bf2f(rbP[kk]));
                }
            } else if (kk == 4) {
                if (doProd) {
                    uint2 sv;
                    sv.x = silu2(bf2f(rbP[0]), bf2f(rbP[1]));
                    sv.y = silu2(bf2f(rbP[2]), bf2f(rbP[3]));
                    *(uint2*)&frag[fbP + pbase_silu] = sv;
                }
            } else {
                int i = kk - 5;
                int s = (cc + 2) * 16 + sg * 4 + i;
                s = (s < HS_) ? s : (HS_ - 1);
                rbL[i] = h1t[(size_t)s * M_ + rbase + pr];
            }
            do_mfma(w0, w1, a0, a1);
            if (kk < 8) { a0 = na0; a1 = na1; }
        }
        __syncthreads();
    };

    unsigned short rbA[4], rbB[4];
#pragma unroll
    for (int i = 0; i < 4; i++) {
        rbA[i] = h1t[(size_t)(sg * 4 + i) * M_ + rbase + pr];
        rbB[i] = h1t[(size_t)(16 + sg * 4 + i) * M_ + rbase + pr];
    }
    produce(0, rbA);            // chunk 0 -> frag[0]
    __syncthreads();

    for (int c2 = 0; c2 < 12; c2++) {        // chunks 0..23
        body(2 * c2,     rbB, rbA);
        body(2 * c2 + 1, rbA, rbB);
    }

    // epilogue: out[b,p,c] = acc + b2[p] + x[b,p,c]
    int b = blk / 12;
    int c0 = (blk % 12) * 64;
#pragma unroll
    for (int nt = 0; nt < 2; nt++) {
        if (nt < ntn) {
            int p0 = (nt0 + nt) * 32 + 4 * half;
#pragma unroll
            for (int reg = 0; reg < 16; reg++) {
                int p = p0 + (reg & 3) + 8 * (reg >> 2);
                if (p < P_) {
                    float bv = b2[p];
#pragma unroll
                    for (int rt = 0; rt < 2; rt++) {
                        size_t off = ((size_t)b * P_ + p) * C_ + c0 + rt * 32 + l31;
                        out[off] = acc[rt][nt][reg] + bv + x[off];
                    }
                }
            }
        }
    }
}

extern "C" void kernel_launch(void* const* d_in, const int* in_sizes, int n_in,
                              void* d_out, int out_size, void* d_ws, size_t ws_size,
                              hipStream_t stream) {
    const float* x   = (const float*)d_in[0];
    const float* w1s = (const float*)d_in[1];
    const float* w1b = (const float*)d_in[2];
    const float* b1  = (const float*)d_in[3];
    const float* w2s = (const float*)d_in[4];
    const float* w2b = (const float*)d_in[5];
    const float* b2  = (const float*)d_in[6];
    float* out = (float*)d_out;

    unsigned short* h1t = (unsigned short*)d_ws;            // 37.75 MB bf16 [n][r]
    unsigned short* w1p = h1t + H1_ELEMS;
    unsigned short* w2p = w1p + W1P_ELEMS;                  // total ~40.7 MB

    int pack_blocks = (int)((W1P_ELEMS + W2P_ELEMS) / 256);
    pack_w_kernel<<<pack_blocks, 256, 0, stream>>>(w1s, w1b, w2s, w2b, w1p, w2p);
    fc1_kernel<<<M_ / 64, 256, 0, stream>>>(x, w1p, b1, h1t);
    fc2_kernel<<<M_ / 64, 256, 0, stream>>>(h1t, w2p, b2, x, out);
}

// Round 3
// 248.466 us; speedup vs baseline: 1.2893x; 1.1216x over previous
//
#include <hip/hip_runtime.h>
#include <cstdint>

#define B_  64
#define P_  196
#define C_  768
#define HS_ 384
#define M_  49152
#define RT_ 96            // r-columns per block (3 rt of 32)
#define NB_ (M_ / RT_)    // 512 blocks = exactly 2/CU

// K-chunk = 16 scalars -> 8 rbf tiles (k16) + 1 silu tile per chunk.
// fc1: 13 chunks (12 full + tail{2 rbf,1 silu}) => KT1 = 111 tiles
// fc2: 24 chunks => KT2 = 216 tiles
#define NC1 13
#define KT1 111
#define NT1 12
#define NC2 24
#define KT2 216
#define NT2 7

#define H1_ELEMS  ((size_t)M_ * HS_)
#define W1P_ELEMS ((size_t)KT1 * NT1 * 512) // 681,984
#define W2P_ELEMS ((size_t)KT2 * NT2 * 512) // 774,144

typedef __attribute__((ext_vector_type(8)))  short short8;
typedef __attribute__((ext_vector_type(16))) float f32x16;

#define MFMA(w, a, c) __builtin_amdgcn_mfma_f32_32x32x16_bf16((w), (a), (c), 0, 0, 0)

static __device__ __forceinline__ float bf2f(unsigned short u) {
    union { unsigned int i; float f; } v; v.i = ((unsigned int)u) << 16; return v.f;
}
static __device__ __forceinline__ unsigned short f2bf_rne(float f) {
    union { float f; unsigned int i; } v; v.f = f;
    unsigned int r = v.i + 0x7FFFu + ((v.i >> 16) & 1u);
    return (unsigned short)(r >> 16);
}
static __device__ __forceinline__ unsigned int pack2(float a, float b) {
    unsigned int ua = __float_as_uint(a) + 0x8000u;
    unsigned int ub = __float_as_uint(b) + 0x8000u;
    return __builtin_amdgcn_perm(ub, ua, 0x07060302u);  // [a | b] (a = low ushort)
}
// 8 RBF basis: exp(-(3.5s+3.5-j)^2) = exp2(-(u_j)^2), u_j = A*s+A - j*R,
// R = sqrt(log2 e).
static __device__ __forceinline__ short8 rbf8(float s) {
    const float Rr = 1.2011224087864498f;     // sqrt(log2 e)
    const float Aa = 4.2039284307525743f;     // 3.5 * Rr
    float t1 = __builtin_fmaf(Aa, s, Aa);
    union { short8 s8; unsigned int u[4]; } r;
#pragma unroll
    for (int q = 0; q < 4; q++) {
        float u0 = t1 - (float)(2 * q) * Rr;
        float u1 = t1 - (float)(2 * q + 1) * Rr;
        r.u[q] = pack2(__builtin_amdgcn_exp2f(-u0 * u0),
                       __builtin_amdgcn_exp2f(-u1 * u1));
    }
    return r.s8;
}
static __device__ __forceinline__ unsigned int silu2(float a, float b) {
    const float L2E = 1.4426950408889634f;
    float fa = a * __builtin_amdgcn_rcpf(1.f + __builtin_amdgcn_exp2f(-L2E * a));
    float fb = b * __builtin_amdgcn_rcpf(1.f + __builtin_amdgcn_exp2f(-L2E * b));
    return pack2(fa, fb);
}

// Weights packed as A-operand frags in consumption order (unchanged):
// w[tt][nt][lane][j] = W[n = nt*32+(lane&31)][k_logical(tt, khalf=lane>>5, j)]
__global__ void pack_w_kernel(const float* __restrict__ w1s,
                              const float* __restrict__ w1b,
                              const float* __restrict__ w2s,
                              const float* __restrict__ w2b,
                              unsigned short* __restrict__ w1p,
                              unsigned short* __restrict__ w2p) {
    size_t idx = (size_t)blockIdx.x * 256 + threadIdx.x;
    if (idx < W1P_ELEMS) {
        int j    = idx & 7;
        int lane = (idx >> 3) & 63;
        int lin  = idx >> 9;             // tt*NT1 + nt
        int nt   = lin % NT1;
        int tt   = lin / NT1;
        int cc   = (tt < 108) ? tt / 9 : 12;
        int kk   = (tt < 108) ? tt % 9 : (tt - 108);
        int ktl  = (cc < 12) ? kk : ((kk < 2) ? kk : 8);
        int n = nt * 32 + (lane & 31);
        int khalf = lane >> 5;
        float v = 0.f;
        if (ktl < 8) {
            int p = cc * 16 + ktl * 2 + khalf;
            if (p < P_) v = w1s[(size_t)n * 1568 + p * 8 + j];
        } else {
            int p = cc * 16 + khalf * 8 + j;
            if (p < P_) v = w1b[(size_t)n * 196 + p];
        }
        w1p[idx] = f2bf_rne(v);
    } else {
        size_t idx2 = idx - W1P_ELEMS;
        if (idx2 < W2P_ELEMS) {
            int j    = idx2 & 7;
            int lane = (idx2 >> 3) & 63;
            int lin  = idx2 >> 9;        // tt*NT2 + nt
            int nt   = lin % NT2;
            int tt   = lin / NT2;
            int cc   = tt / 9;
            int ktl  = tt % 9;
            int n = nt * 32 + (lane & 31);
            int khalf = lane >> 5;
            float v = 0.f;
            if (n < P_) {
                if (ktl < 8) {
                    int s = cc * 16 + ktl * 2 + khalf;
                    v = w2s[(size_t)n * 3072 + s * 8 + j];
                } else {
                    int s = cc * 16 + khalf * 8 + j;
                    v = w2b[(size_t)n * 384 + s];
                }
            }
            w2p[idx2] = f2bf_rne(v);
        }
    }
}

// frag LDS tile: [rt 3][khalf 2][col 32][8] = 1536 ushort; 9 tiles/buf.
#define TS_  1536
#define FB_  (9 * TS_)   // 13824 ushort per buffer

// R3 structure: r-tile 96 (3 rt), grid NB_=512 = exactly 2 blocks/CU (no
// tail round). 9 MFMA per kk (3 rt x 3 nt for fc1). Produce/load slices
// interleaved into the kk loop as in R2; weight prefetch depth 2 to hold
// register budget under 256 (acc 144 AGPR fc1).
//
// Produce coverage of 96 cols x 16 scalars by 256 threads:
//   mapping A: colA = tid&63 (rt 0,1), scalars scA*4+i (scA = tid>>6), 4/thread
//   mapping B: colB = 64+(tid&31) (rt 2), scalars scB*2+i (scB = tid>>5), 2/thread

// fc1: D[n][r] = W1 * act(x)^T; writes h1t[n][r].
__global__ __launch_bounds__(256, 2)
void fc1_kernel(const float* __restrict__ x,
                const unsigned short* __restrict__ w1p,
                const float* __restrict__ b1,
                unsigned short* __restrict__ h1t) {
    __shared__ __align__(16) unsigned short frag[2 * FB_];
    int blk = blockIdx.x;
    int tid = threadIdx.x;
    int b   = blk >> 3;
    int c0  = (blk & 7) * RT_;
    const float* xb = x + (size_t)b * (P_ * C_);

    int colA = tid & 63, scA = tid >> 6;
    int colB = 64 + (tid & 31), scB = tid >> 5;
    int pbase_rbfA  = ((colA >> 5) << 9) + (colA & 31) * 8;
    int pbase_rbfB  = 1024 + (colB & 31) * 8;
    int pbase_siluA = 8 * TS_ + ((colA >> 5) << 9) + ((scA >> 1) << 8) + (colA & 31) * 8 + (scA & 1) * 4;
    int pbase_siluB = 8 * TS_ + 1024 + ((scB >> 2) << 8) + (colB & 31) * 8 + (scB & 3) * 2;

    int wave = tid >> 6, lane = tid & 63;
    int l31 = lane & 31, half = lane >> 5;
    int nt0 = wave * 3;

    f32x16 acc[3][3];   // [rt][nt]
#pragma unroll
    for (int rt = 0; rt < 3; rt++)
#pragma unroll
        for (int nt = 0; nt < 3; nt++)
#pragma unroll
            for (int i = 0; i < 16; i++) acc[rt][nt][i] = 0.f;

    const short8* wp = (const short8*)w1p;
    short8 wbuf[2][3];

    auto wload = [&](int d, const short8* wt0, int kk) {
        const short8* wt = wt0 + (size_t)kk * (NT1 * 64);
        wbuf[d][0] = wt[0]; wbuf[d][1] = wt[64]; wbuf[d][2] = wt[128];
    };
    auto do_mfma = [&](short8 w0, short8 w1, short8 w2,
                       short8 a0, short8 a1, short8 a2) {
        acc[0][0] = MFMA(w0, a0, acc[0][0]); acc[1][0] = MFMA(w0, a1, acc[1][0]); acc[2][0] = MFMA(w0, a2, acc[2][0]);
        acc[0][1] = MFMA(w1, a0, acc[0][1]); acc[1][1] = MFMA(w1, a1, acc[1][1]); acc[2][1] = MFMA(w1, a2, acc[2][1]);
        acc[0][2] = MFMA(w2, a0, acc[0][2]); acc[1][2] = MFMA(w2, a1, acc[1][2]); acc[2][2] = MFMA(w2, a2, acc[2][2]);
    };
    // full produce (prologue only)
    auto produce = [&](int fb, const float (&ra)[4], const float (&rb2)[2]) {
#pragma unroll
        for (int i = 0; i < 4; i++) {
            int sl = scA * 4 + i;
            *(short8*)&frag[fb + (sl >> 1) * TS_ + ((sl & 1) << 8) + pbase_rbfA] = rbf8(ra[i]);
        }
#pragma unroll
        for (int i = 0; i < 2; i++) {
            int sl = scB * 2 + i;
            *(short8*)&frag[fb + (sl >> 1) * TS_ + ((sl & 1) << 8) + pbase_rbfB] = rbf8(rb2[i]);
        }
        uint2 sv;
        sv.x = silu2(ra[0], ra[1]);
        sv.y = silu2(ra[2], ra[3]);
        *(uint2*)&frag[fb + pbase_siluA] = sv;
        *(unsigned int*)&frag[fb + pbase_siluB] = silu2(rb2[0], rb2[1]);
    };
    // body(cc): consume chunk cc; produce chunk cc+1; load chunk cc+2.
    auto body = [&](int cc, const float (&rbPA)[4], const float (&rbPB)[2],
                    float (&rbLA)[4], float (&rbLB)[2]) {
        const short8* wt0 = wp + ((size_t)(cc * 9) * NT1 + nt0) * 64 + lane;
        wload(0, wt0, 0); wload(1, wt0, 1);
        int fbP = ((cc + 1) & 1) * FB_;
        const unsigned short* fg = &frag[(cc & 1) * FB_];
        short8 a0 = *(const short8*)&fg[lane * 8];
        short8 a1 = *(const short8*)&fg[512 + lane * 8];
        short8 a2 = *(const short8*)&fg[1024 + lane * 8];
#pragma unroll
        for (int kk = 0; kk < 9; kk++) {
            short8 na0, na1, na2;
            if (kk < 8) {
                na0 = *(const short8*)&fg[(kk + 1) * TS_ + lane * 8];
                na1 = *(const short8*)&fg[(kk + 1) * TS_ + 512 + lane * 8];
                na2 = *(const short8*)&fg[(kk + 1) * TS_ + 1024 + lane * 8];
            }
            short8 w0 = wbuf[kk & 1][0], w1 = wbuf[kk & 1][1], w2 = wbuf[kk & 1][2];
            if (kk < 7) wload(kk & 1, wt0, kk + 2);
            if (kk < 4) {                 // produce: A-rbf slice kk
                int sl = scA * 4 + kk;
                *(short8*)&frag[fbP + (sl >> 1) * TS_ + ((sl & 1) << 8) + pbase_rbfA] = rbf8(rbPA[kk]);
            } else if (kk == 4) {         // produce: B-rbf slices
#pragma unroll
                for (int i = 0; i < 2; i++) {
                    int sl = scB * 2 + i;
                    *(short8*)&frag[fbP + (sl >> 1) * TS_ + ((sl & 1) << 8) + pbase_rbfB] = rbf8(rbPB[i]);
                }
            } else if (kk == 5) {         // produce: silu tiles
                uint2 sv;
                sv.x = silu2(rbPA[0], rbPA[1]);
                sv.y = silu2(rbPA[2], rbPA[3]);
                *(uint2*)&frag[fbP + pbase_siluA] = sv;
                *(unsigned int*)&frag[fbP + pbase_siluB] = silu2(rbPB[0], rbPB[1]);
            } else if (kk == 6) {         // loads for chunk cc+2
#pragma unroll
                for (int i = 0; i < 2; i++) {
                    int p = (cc + 2) * 16 + scA * 4 + i;
                    p = (p < P_) ? p : (P_ - 1);
                    rbLA[i] = xb[(size_t)p * C_ + c0 + colA];
                }
            } else if (kk == 7) {
#pragma unroll
                for (int i = 2; i < 4; i++) {
                    int p = (cc + 2) * 16 + scA * 4 + i;
                    p = (p < P_) ? p : (P_ - 1);
                    rbLA[i] = xb[(size_t)p * C_ + c0 + colA];
                }
            } else {
#pragma unroll
                for (int i = 0; i < 2; i++) {
                    int p = (cc + 2) * 16 + scB * 2 + i;
                    p = (p < P_) ? p : (P_ - 1);
                    rbLB[i] = xb[(size_t)p * C_ + c0 + colB];
                }
            }
            do_mfma(w0, w1, w2, a0, a1, a2);
            if (kk < 8) { a0 = na0; a1 = na1; a2 = na2; }
        }
        __syncthreads();
    };

    float rbA_A[4], rbB_A[4], rbA_B[2], rbB_B[2];
#pragma unroll
    for (int i = 0; i < 4; i++) {
        rbA_A[i] = xb[(size_t)(scA * 4 + i) * C_ + c0 + colA];
        rbB_A[i] = xb[(size_t)(16 + scA * 4 + i) * C_ + c0 + colA];
    }
#pragma unroll
    for (int i = 0; i < 2; i++) {
        rbA_B[i] = xb[(size_t)(scB * 2 + i) * C_ + c0 + colB];
        rbB_B[i] = xb[(size_t)(16 + scB * 2 + i) * C_ + c0 + colB];
    }
    produce(0, rbA_A, rbA_B);   // chunk 0 -> frag[0]
    __syncthreads();

    for (int c2 = 0; c2 < 6; c2++) {          // chunks 0..11
        body(2 * c2,     rbB_A, rbB_B, rbA_A, rbA_B);
        body(2 * c2 + 1, rbA_A, rbA_B, rbB_A, rbB_B);
    }
    // tail: consume chunk 12 (tiles ktl {0,1,8}; weights linear 108..110)
    {
        const short8* wt0 = wp + ((size_t)108 * NT1 + nt0) * 64 + lane;
        wload(0, wt0, 0); wload(1, wt0, 1);
        const unsigned short* fg = &frag[0];  // chunk 12 parity 0
#pragma unroll
        for (int kk = 0; kk < 3; kk++) {
            short8 w0 = wbuf[kk & 1][0], w1 = wbuf[kk & 1][1], w2 = wbuf[kk & 1][2];
            if (kk == 0) wload(0, wt0, 2);
            int ktl = (kk < 2) ? kk : 8;
            short8 a0 = *(const short8*)&fg[ktl * TS_ + lane * 8];
            short8 a1 = *(const short8*)&fg[ktl * TS_ + 512 + lane * 8];
            short8 a2 = *(const short8*)&fg[ktl * TS_ + 1024 + lane * 8];
            do_mfma(w0, w1, w2, a0, a1, a2);
        }
    }

    // epilogue: h1t[n][r]
#pragma unroll
    for (int nt = 0; nt < 3; nt++) {
        int n0 = (nt0 + nt) * 32 + 4 * half;
#pragma unroll
        for (int reg = 0; reg < 16; reg++) {
            int n = n0 + (reg & 3) + 8 * (reg >> 2);
            float bv = b1[n];
#pragma unroll
            for (int rt = 0; rt < 3; rt++) {
                h1t[(size_t)n * M_ + blk * RT_ + rt * 32 + l31] = f2bf_rne(acc[rt][nt][reg] + bv);
            }
        }
    }
}

// fc2: D[p][r] = W2 * act(h1)^T; out = D + b2 + x.
__global__ __launch_bounds__(256, 2)
void fc2_kernel(const unsigned short* __restrict__ h1t,
                const unsigned short* __restrict__ w2p,
                const float* __restrict__ b2,
                const float* __restrict__ x,
                float* __restrict__ out) {
    __shared__ __align__(16) unsigned short frag[2 * FB_];
    int blk = blockIdx.x;
    int tid = threadIdx.x;
    int rbase = blk * RT_;

    int colA = tid & 63, scA = tid >> 6;
    int colB = 64 + (tid & 31), scB = tid >> 5;
    int pbase_rbfA  = ((colA >> 5) << 9) + (colA & 31) * 8;
    int pbase_rbfB  = 1024 + (colB & 31) * 8;
    int pbase_siluA = 8 * TS_ + ((colA >> 5) << 9) + ((scA >> 1) << 8) + (colA & 31) * 8 + (scA & 1) * 4;
    int pbase_siluB = 8 * TS_ + 1024 + ((scB >> 2) << 8) + (colB & 31) * 8 + (scB & 3) * 2;

    int wave = tid >> 6, lane = tid & 63;
    int l31 = lane & 31, half = lane >> 5;
    int nt0 = wave * 2;
    int ntn = (wave < 3) ? 2 : 1;
    int off1 = (ntn > 1) ? 64 : 0;           // wave 3 dups its tile (discarded)

    f32x16 acc[3][2];   // [rt][nt]
#pragma unroll
    for (int rt = 0; rt < 3; rt++)
#pragma unroll
        for (int nt = 0; nt < 2; nt++)
#pragma unroll
            for (int i = 0; i < 16; i++) acc[rt][nt][i] = 0.f;

    const short8* wp = (const short8*)w2p;
    short8 wbuf[2][2];

    auto wload = [&](int d, const short8* wt0, int kk) {
        const short8* wt = wt0 + (size_t)kk * (NT2 * 64);
        wbuf[d][0] = wt[0]; wbuf[d][1] = wt[off1];
    };
    auto do_mfma = [&](short8 w0, short8 w1, short8 a0, short8 a1, short8 a2) {
        acc[0][0] = MFMA(w0, a0, acc[0][0]); acc[1][0] = MFMA(w0, a1, acc[1][0]); acc[2][0] = MFMA(w0, a2, acc[2][0]);
        if (ntn == 2) {
            acc[0][1] = MFMA(w1, a0, acc[0][1]); acc[1][1] = MFMA(w1, a1, acc[1][1]); acc[2][1] = MFMA(w1, a2, acc[2][1]);
        }
    };
    auto produce = [&](int fb, const unsigned short (&ra)[4], const unsigned short (&rb2)[2]) {
        float v0 = bf2f(ra[0]), v1 = bf2f(ra[1]), v2 = bf2f(ra[2]), v3 = bf2f(ra[3]);
        float u0 = bf2f(rb2[0]), u1 = bf2f(rb2[1]);
        float vv[4] = {v0, v1, v2, v3};
#pragma unroll
        for (int i = 0; i < 4; i++) {
            int sl = scA * 4 + i;
            *(short8*)&frag[fb + (sl >> 1) * TS_ + ((sl & 1) << 8) + pbase_rbfA] = rbf8(vv[i]);
        }
        float uu[2] = {u0, u1};
#pragma unroll
        for (int i = 0; i < 2; i++) {
            int sl = scB * 2 + i;
            *(short8*)&frag[fb + (sl >> 1) * TS_ + ((sl & 1) << 8) + pbase_rbfB] = rbf8(uu[i]);
        }
        uint2 sv;
        sv.x = silu2(v0, v1);
        sv.y = silu2(v2, v3);
        *(uint2*)&frag[fb + pbase_siluA] = sv;
        *(unsigned int*)&frag[fb + pbase_siluB] = silu2(u0, u1);
    };
    auto body = [&](int cc, const unsigned short (&rbPA)[4], const unsigned short (&rbPB)[2],
                    unsigned short (&rbLA)[4], unsigned short (&rbLB)[2]) {
        bool doProd = (cc + 1 < NC2);
        const short8* wt0 = wp + ((size_t)(cc * 9) * NT2 + nt0) * 64 + lane;
        wload(0, wt0, 0); wload(1, wt0, 1);
        int fbP = ((cc + 1) & 1) * FB_;
        const unsigned short* fg = &frag[(cc & 1) * FB_];
        short8 a0 = *(const short8*)&fg[lane * 8];
        short8 a1 = *(const short8*)&fg[512 + lane * 8];
        short8 a2 = *(const short8*)&fg[1024 + lane * 8];
#pragma unroll
        for (int kk = 0; kk < 9; kk++) {
            short8 na0, na1, na2;
            if (kk < 8) {
                na0 = *(const short8*)&fg[(kk + 1) * TS_ + lane * 8];
                na1 = *(const short8*)&fg[(kk + 1) * TS_ + 512 + lane * 8];
                na2 = *(const short8*)&fg[(kk + 1) * TS_ + 1024 + lane * 8];
            }
            short8 w0 = wbuf[kk & 1][0], w1 = wbuf[kk & 1][1];
            if (kk < 7) wload(kk & 1, wt0, kk + 2);
            if (kk < 4) {
                if (doProd) {
                    int sl = scA * 4 + kk;
                    *(short8*)&frag[fbP + (sl >> 1) * TS_ + ((sl & 1) << 8) + pbase_rbfA] =
                        rbf8(bf2f(rbPA[kk]));
                }
            } else if (kk == 4) {
                if (doProd) {
#pragma unroll
                    for (int i = 0; i < 2; i++) {
                        int sl = scB * 2 + i;
                        *(short8*)&frag[fbP + (sl >> 1) * TS_ + ((sl & 1) << 8) + pbase_rbfB] =
                            rbf8(bf2f(rbPB[i]));
                    }
                }
            } else if (kk == 5) {
                if (doProd) {
                    uint2 sv;
                    sv.x = silu2(bf2f(rbPA[0]), bf2f(rbPA[1]));
                    sv.y = silu2(bf2f(rbPA[2]), bf2f(rbPA[3]));
                    *(uint2*)&frag[fbP + pbase_siluA] = sv;
                    *(unsigned int*)&frag[fbP + pbase_siluB] = silu2(bf2f(rbPB[0]), bf2f(rbPB[1]));
                }
            } else if (kk == 6) {
#pragma unroll
                for (int i = 0; i < 2; i++) {
                    int s = (cc + 2) * 16 + scA * 4 + i;
                    s = (s < HS_) ? s : (HS_ - 1);
                    rbLA[i] = h1t[(size_t)s * M_ + rbase + colA];
                }
            } else if (kk == 7) {
#pragma unroll
                for (int i = 2; i < 4; i++) {
                    int s = (cc + 2) * 16 + scA * 4 + i;
                    s = (s < HS_) ? s : (HS_ - 1);
                    rbLA[i] = h1t[(size_t)s * M_ + rbase + colA];
                }
            } else {
#pragma unroll
                for (int i = 0; i < 2; i++) {
                    int s = (cc + 2) * 16 + scB * 2 + i;
                    s = (s < HS_) ? s : (HS_ - 1);
                    rbLB[i] = h1t[(size_t)s * M_ + rbase + colB];
                }
            }
            do_mfma(w0, w1, a0, a1, a2);
            if (kk < 8) { a0 = na0; a1 = na1; a2 = na2; }
        }
        __syncthreads();
    };

    unsigned short rbA_A[4], rbB_A[4], rbA_B[2], rbB_B[2];
#pragma unroll
    for (int i = 0; i < 4; i++) {
        rbA_A[i] = h1t[(size_t)(scA * 4 + i) * M_ + rbase + colA];
        rbB_A[i] = h1t[(size_t)(16 + scA * 4 + i) * M_ + rbase + colA];
    }
#pragma unroll
    for (int i = 0; i < 2; i++) {
        rbA_B[i] = h1t[(size_t)(scB * 2 + i) * M_ + rbase + colB];
        rbB_B[i] = h1t[(size_t)(16 + scB * 2 + i) * M_ + rbase + colB];
    }
    produce(0, rbA_A, rbA_B);   // chunk 0 -> frag[0]
    __syncthreads();

    for (int c2 = 0; c2 < 12; c2++) {        // chunks 0..23
        body(2 * c2,     rbB_A, rbB_B, rbA_A, rbA_B);
        body(2 * c2 + 1, rbA_A, rbA_B, rbB_A, rbB_B);
    }

    // epilogue: out[b,p,c] = acc + b2[p] + x[b,p,c]
    int b = blk >> 3;
    int c0 = (blk & 7) * RT_;
#pragma unroll
    for (int nt = 0; nt < 2; nt++) {
        if (nt < ntn) {
            int p0 = (nt0 + nt) * 32 + 4 * half;
#pragma unroll
            for (int reg = 0; reg < 16; reg++) {
                int p = p0 + (reg & 3) + 8 * (reg >> 2);
                if (p < P_) {
                    float bv = b2[p];
#pragma unroll
                    for (int rt = 0; rt < 3; rt++) {
                        size_t off = ((size_t)b * P_ + p) * C_ + c0 + rt * 32 + l31;
                        out[off] = acc[rt][nt][reg] + bv + x[off];
                    }
                }
            }
        }
    }
}

extern "C" void kernel_launch(void* const* d_in, const int* in_sizes, int n_in,
                              void* d_out, int out_size, void* d_ws, size_t ws_size,
                              hipStream_t stream) {
    const float* x   = (const float*)d_in[0];
    const float* w1s = (const float*)d_in[1];
    const float* w1b = (const float*)d_in[2];
    const float* b1  = (const float*)d_in[3];
    const float* w2s = (const float*)d_in[4];
    const float* w2b = (const float*)d_in[5];
    const float* b2  = (const float*)d_in[6];
    float* out = (float*)d_out;

    unsigned short* h1t = (unsigned short*)d_ws;            // 37.75 MB bf16 [n][r]
    unsigned short* w1p = h1t + H1_ELEMS;
    unsigned short* w2p = w1p + W1P_ELEMS;                  // total ~40.7 MB

    int pack_blocks = (int)((W1P_ELEMS + W2P_ELEMS) / 256);
    pack_w_kernel<<<pack_blocks, 256, 0, stream>>>(w1s, w1b, w2s, w2b, w1p, w2p);
    fc1_kernel<<<NB_, 256, 0, stream>>>(x, w1p, b1, h1t);
    fc2_kernel<<<NB_, 256, 0, stream>>>(h1t, w2p, b2, x, out);
}

// Round 4
// 243.440 us; speedup vs baseline: 1.3159x; 1.0206x over previous
//
#include <hip/hip_runtime.h>
#include <cstdint>

#define B_  64
#define P_  196
#define C_  768
#define HS_ 384
#define M_  49152
#define RT_ 96            // r-columns per block (3 rt of 32)
#define NB_ (M_ / RT_)    // 512 blocks = exactly 2/CU

// K-chunk = 16 scalars -> 8 rbf tiles (k16) + 1 silu tile per chunk.
// fc1: 13 chunks (12 full + tail{2 rbf,1 silu}) => KT1 = 111 tiles
// fc2: 24 chunks => KT2 = 216 tiles
#define NC1 13
#define KT1 111
#define NT1 12
#define NC2 24
#define KT2 216
#define NT2 7

#define H1_ELEMS  ((size_t)M_ * HS_)
#define W1P_ELEMS ((size_t)KT1 * NT1 * 512) // 681,984
#define W2P_ELEMS ((size_t)KT2 * NT2 * 512) // 774,144

typedef __attribute__((ext_vector_type(8)))  short short8;
typedef __attribute__((ext_vector_type(16))) float f32x16;

#define MFMA(w, a, c) __builtin_amdgcn_mfma_f32_32x32x16_bf16((w), (a), (c), 0, 0, 0)

static __device__ __forceinline__ float bf2f(unsigned short u) {
    union { unsigned int i; float f; } v; v.i = ((unsigned int)u) << 16; return v.f;
}
static __device__ __forceinline__ unsigned short f2bf_rne(float f) {
    union { float f; unsigned int i; } v; v.f = f;
    unsigned int r = v.i + 0x7FFFu + ((v.i >> 16) & 1u);
    return (unsigned short)(r >> 16);
}
static __device__ __forceinline__ unsigned int pack2(float a, float b) {
    unsigned int ua = __float_as_uint(a) + 0x8000u;
    unsigned int ub = __float_as_uint(b) + 0x8000u;
    return __builtin_amdgcn_perm(ub, ua, 0x07060302u);  // [a | b] (a = low ushort)
}
// 8 RBF basis: exp(-(3.5s+3.5-j)^2) = exp2(-(u_j)^2), u_j = A*s+A - j*R,
// R = sqrt(log2 e).
static __device__ __forceinline__ short8 rbf8(float s) {
    const float Rr = 1.2011224087864498f;     // sqrt(log2 e)
    const float Aa = 4.2039284307525743f;     // 3.5 * Rr
    float t1 = __builtin_fmaf(Aa, s, Aa);
    union { short8 s8; unsigned int u[4]; } r;
#pragma unroll
    for (int q = 0; q < 4; q++) {
        float u0 = t1 - (float)(2 * q) * Rr;
        float u1 = t1 - (float)(2 * q + 1) * Rr;
        r.u[q] = pack2(__builtin_amdgcn_exp2f(-u0 * u0),
                       __builtin_amdgcn_exp2f(-u1 * u1));
    }
    return r.s8;
}
static __device__ __forceinline__ unsigned int silu2(float a, float b) {
    const float L2E = 1.4426950408889634f;
    float fa = a * __builtin_amdgcn_rcpf(1.f + __builtin_amdgcn_exp2f(-L2E * a));
    float fb = b * __builtin_amdgcn_rcpf(1.f + __builtin_amdgcn_exp2f(-L2E * b));
    return pack2(fa, fb);
}

// Raw barrier with lgkmcnt-only fence: LDS writes must be visible to other
// waves, but private vmem loads (weights/rbL -> registers) need NO drain at
// a barrier. __syncthreads() would emit s_waitcnt vmcnt(0), forcing every
// wave to eat full L3 latency for rbL prefetches issued ~1 kk earlier.
// The compiler's per-dependency vmcnt(N) waits before wbuf/rbL uses remain.
static __device__ __forceinline__ void block_sync_lds() {
    __builtin_amdgcn_sched_barrier(0);
    asm volatile("s_waitcnt lgkmcnt(0)" ::: "memory");
    __builtin_amdgcn_s_barrier();
    __builtin_amdgcn_sched_barrier(0);
}

// Weights packed as A-operand frags in consumption order (unchanged):
// w[tt][nt][lane][j] = W[n = nt*32+(lane&31)][k_logical(tt, khalf=lane>>5, j)]
__global__ void pack_w_kernel(const float* __restrict__ w1s,
                              const float* __restrict__ w1b,
                              const float* __restrict__ w2s,
                              const float* __restrict__ w2b,
                              unsigned short* __restrict__ w1p,
                              unsigned short* __restrict__ w2p) {
    size_t idx = (size_t)blockIdx.x * 256 + threadIdx.x;
    if (idx < W1P_ELEMS) {
        int j    = idx & 7;
        int lane = (idx >> 3) & 63;
        int lin  = idx >> 9;             // tt*NT1 + nt
        int nt   = lin % NT1;
        int tt   = lin / NT1;
        int cc   = (tt < 108) ? tt / 9 : 12;
        int kk   = (tt < 108) ? tt % 9 : (tt - 108);
        int ktl  = (cc < 12) ? kk : ((kk < 2) ? kk : 8);
        int n = nt * 32 + (lane & 31);
        int khalf = lane >> 5;
        float v = 0.f;
        if (ktl < 8) {
            int p = cc * 16 + ktl * 2 + khalf;
            if (p < P_) v = w1s[(size_t)n * 1568 + p * 8 + j];
        } else {
            int p = cc * 16 + khalf * 8 + j;
            if (p < P_) v = w1b[(size_t)n * 196 + p];
        }
        w1p[idx] = f2bf_rne(v);
    } else {
        size_t idx2 = idx - W1P_ELEMS;
        if (idx2 < W2P_ELEMS) {
            int j    = idx2 & 7;
            int lane = (idx2 >> 3) & 63;
            int lin  = idx2 >> 9;        // tt*NT2 + nt
            int nt   = lin % NT2;
            int tt   = lin / NT2;
            int cc   = tt / 9;
            int ktl  = tt % 9;
            int n = nt * 32 + (lane & 31);
            int khalf = lane >> 5;
            float v = 0.f;
            if (n < P_) {
                if (ktl < 8) {
                    int s = cc * 16 + ktl * 2 + khalf;
                    v = w2s[(size_t)n * 3072 + s * 8 + j];
                } else {
                    int s = cc * 16 + khalf * 8 + j;
                    v = w2b[(size_t)n * 384 + s];
                }
            }
            w2p[idx2] = f2bf_rne(v);
        }
    }
}

// frag LDS tile: [rt 3][khalf 2][col 32][8] = 1536 ushort; 9 tiles/buf.
#define TS_  1536
#define FB_  (9 * TS_)   // 13824 ushort per buffer

// R4: identical to R3 except the per-chunk __syncthreads() is replaced by
// block_sync_lds() (no vmcnt(0) drain across the barrier).
//
// Produce coverage of 96 cols x 16 scalars by 256 threads:
//   mapping A: colA = tid&63 (rt 0,1), scalars scA*4+i (scA = tid>>6), 4/thread
//   mapping B: colB = 64+(tid&31) (rt 2), scalars scB*2+i (scB = tid>>5), 2/thread

// fc1: D[n][r] = W1 * act(x)^T; writes h1t[n][r].
__global__ __launch_bounds__(256, 2)
void fc1_kernel(const float* __restrict__ x,
                const unsigned short* __restrict__ w1p,
                const float* __restrict__ b1,
                unsigned short* __restrict__ h1t) {
    __shared__ __align__(16) unsigned short frag[2 * FB_];
    int blk = blockIdx.x;
    int tid = threadIdx.x;
    int b   = blk >> 3;
    int c0  = (blk & 7) * RT_;
    const float* xb = x + (size_t)b * (P_ * C_);

    int colA = tid & 63, scA = tid >> 6;
    int colB = 64 + (tid & 31), scB = tid >> 5;
    int pbase_rbfA  = ((colA >> 5) << 9) + (colA & 31) * 8;
    int pbase_rbfB  = 1024 + (colB & 31) * 8;
    int pbase_siluA = 8 * TS_ + ((colA >> 5) << 9) + ((scA >> 1) << 8) + (colA & 31) * 8 + (scA & 1) * 4;
    int pbase_siluB = 8 * TS_ + 1024 + ((scB >> 2) << 8) + (colB & 31) * 8 + (scB & 3) * 2;

    int wave = tid >> 6, lane = tid & 63;
    int l31 = lane & 31, half = lane >> 5;
    int nt0 = wave * 3;

    f32x16 acc[3][3];   // [rt][nt]
#pragma unroll
    for (int rt = 0; rt < 3; rt++)
#pragma unroll
        for (int nt = 0; nt < 3; nt++)
#pragma unroll
            for (int i = 0; i < 16; i++) acc[rt][nt][i] = 0.f;

    const short8* wp = (const short8*)w1p;
    short8 wbuf[2][3];

    auto wload = [&](int d, const short8* wt0, int kk) {
        const short8* wt = wt0 + (size_t)kk * (NT1 * 64);
        wbuf[d][0] = wt[0]; wbuf[d][1] = wt[64]; wbuf[d][2] = wt[128];
    };
    auto do_mfma = [&](short8 w0, short8 w1, short8 w2,
                       short8 a0, short8 a1, short8 a2) {
        acc[0][0] = MFMA(w0, a0, acc[0][0]); acc[1][0] = MFMA(w0, a1, acc[1][0]); acc[2][0] = MFMA(w0, a2, acc[2][0]);
        acc[0][1] = MFMA(w1, a0, acc[0][1]); acc[1][1] = MFMA(w1, a1, acc[1][1]); acc[2][1] = MFMA(w1, a2, acc[2][1]);
        acc[0][2] = MFMA(w2, a0, acc[0][2]); acc[1][2] = MFMA(w2, a1, acc[1][2]); acc[2][2] = MFMA(w2, a2, acc[2][2]);
    };
    // full produce (prologue only)
    auto produce = [&](int fb, const float (&ra)[4], const float (&rb2)[2]) {
#pragma unroll
        for (int i = 0; i < 4; i++) {
            int sl = scA * 4 + i;
            *(short8*)&frag[fb + (sl >> 1) * TS_ + ((sl & 1) << 8) + pbase_rbfA] = rbf8(ra[i]);
        }
#pragma unroll
        for (int i = 0; i < 2; i++) {
            int sl = scB * 2 + i;
            *(short8*)&frag[fb + (sl >> 1) * TS_ + ((sl & 1) << 8) + pbase_rbfB] = rbf8(rb2[i]);
        }
        uint2 sv;
        sv.x = silu2(ra[0], ra[1]);
        sv.y = silu2(ra[2], ra[3]);
        *(uint2*)&frag[fb + pbase_siluA] = sv;
        *(unsigned int*)&frag[fb + pbase_siluB] = silu2(rb2[0], rb2[1]);
    };
    // body(cc): consume chunk cc; produce chunk cc+1; load chunk cc+2.
    auto body = [&](int cc, const float (&rbPA)[4], const float (&rbPB)[2],
                    float (&rbLA)[4], float (&rbLB)[2]) {
        const short8* wt0 = wp + ((size_t)(cc * 9) * NT1 + nt0) * 64 + lane;
        wload(0, wt0, 0); wload(1, wt0, 1);
        int fbP = ((cc + 1) & 1) * FB_;
        const unsigned short* fg = &frag[(cc & 1) * FB_];
        short8 a0 = *(const short8*)&fg[lane * 8];
        short8 a1 = *(const short8*)&fg[512 + lane * 8];
        short8 a2 = *(const short8*)&fg[1024 + lane * 8];
#pragma unroll
        for (int kk = 0; kk < 9; kk++) {
            short8 na0, na1, na2;
            if (kk < 8) {
                na0 = *(const short8*)&fg[(kk + 1) * TS_ + lane * 8];
                na1 = *(const short8*)&fg[(kk + 1) * TS_ + 512 + lane * 8];
                na2 = *(const short8*)&fg[(kk + 1) * TS_ + 1024 + lane * 8];
            }
            short8 w0 = wbuf[kk & 1][0], w1 = wbuf[kk & 1][1], w2 = wbuf[kk & 1][2];
            if (kk < 7) wload(kk & 1, wt0, kk + 2);
            if (kk < 4) {                 // produce: A-rbf slice kk
                int sl = scA * 4 + kk;
                *(short8*)&frag[fbP + (sl >> 1) * TS_ + ((sl & 1) << 8) + pbase_rbfA] = rbf8(rbPA[kk]);
            } else if (kk == 4) {         // produce: B-rbf slices
#pragma unroll
                for (int i = 0; i < 2; i++) {
                    int sl = scB * 2 + i;
                    *(short8*)&frag[fbP + (sl >> 1) * TS_ + ((sl & 1) << 8) + pbase_rbfB] = rbf8(rbPB[i]);
                }
            } else if (kk == 5) {         // produce: silu tiles
                uint2 sv;
                sv.x = silu2(rbPA[0], rbPA[1]);
                sv.y = silu2(rbPA[2], rbPA[3]);
                *(uint2*)&frag[fbP + pbase_siluA] = sv;
                *(unsigned int*)&frag[fbP + pbase_siluB] = silu2(rbPB[0], rbPB[1]);
            } else if (kk == 6) {         // loads for chunk cc+2
#pragma unroll
                for (int i = 0; i < 2; i++) {
                    int p = (cc + 2) * 16 + scA * 4 + i;
                    p = (p < P_) ? p : (P_ - 1);
                    rbLA[i] = xb[(size_t)p * C_ + c0 + colA];
                }
            } else if (kk == 7) {
#pragma unroll
                for (int i = 2; i < 4; i++) {
                    int p = (cc + 2) * 16 + scA * 4 + i;
                    p = (p < P_) ? p : (P_ - 1);
                    rbLA[i] = xb[(size_t)p * C_ + c0 + colA];
                }
            } else {
#pragma unroll
                for (int i = 0; i < 2; i++) {
                    int p = (cc + 2) * 16 + scB * 2 + i;
                    p = (p < P_) ? p : (P_ - 1);
                    rbLB[i] = xb[(size_t)p * C_ + c0 + colB];
                }
            }
            do_mfma(w0, w1, w2, a0, a1, a2);
            if (kk < 8) { a0 = na0; a1 = na1; a2 = na2; }
        }
        block_sync_lds();
    };

    float rbA_A[4], rbB_A[4], rbA_B[2], rbB_B[2];
#pragma unroll
    for (int i = 0; i < 4; i++) {
        rbA_A[i] = xb[(size_t)(scA * 4 + i) * C_ + c0 + colA];
        rbB_A[i] = xb[(size_t)(16 + scA * 4 + i) * C_ + c0 + colA];
    }
#pragma unroll
    for (int i = 0; i < 2; i++) {
        rbA_B[i] = xb[(size_t)(scB * 2 + i) * C_ + c0 + colB];
        rbB_B[i] = xb[(size_t)(16 + scB * 2 + i) * C_ + c0 + colB];
    }
    produce(0, rbA_A, rbA_B);   // chunk 0 -> frag[0]
    block_sync_lds();

    for (int c2 = 0; c2 < 6; c2++) {          // chunks 0..11
        body(2 * c2,     rbB_A, rbB_B, rbA_A, rbA_B);
        body(2 * c2 + 1, rbA_A, rbA_B, rbB_A, rbB_B);
    }
    // tail: consume chunk 12 (tiles ktl {0,1,8}; weights linear 108..110)
    {
        const short8* wt0 = wp + ((size_t)108 * NT1 + nt0) * 64 + lane;
        wload(0, wt0, 0); wload(1, wt0, 1);
        const unsigned short* fg = &frag[0];  // chunk 12 parity 0
#pragma unroll
        for (int kk = 0; kk < 3; kk++) {
            short8 w0 = wbuf[kk & 1][0], w1 = wbuf[kk & 1][1], w2 = wbuf[kk & 1][2];
            if (kk == 0) wload(0, wt0, 2);
            int ktl = (kk < 2) ? kk : 8;
            short8 a0 = *(const short8*)&fg[ktl * TS_ + lane * 8];
            short8 a1 = *(const short8*)&fg[ktl * TS_ + 512 + lane * 8];
            short8 a2 = *(const short8*)&fg[ktl * TS_ + 1024 + lane * 8];
            do_mfma(w0, w1, w2, a0, a1, a2);
        }
    }

    // epilogue: h1t[n][r]
#pragma unroll
    for (int nt = 0; nt < 3; nt++) {
        int n0 = (nt0 + nt) * 32 + 4 * half;
#pragma unroll
        for (int reg = 0; reg < 16; reg++) {
            int n = n0 + (reg & 3) + 8 * (reg >> 2);
            float bv = b1[n];
#pragma unroll
            for (int rt = 0; rt < 3; rt++) {
                h1t[(size_t)n * M_ + blk * RT_ + rt * 32 + l31] = f2bf_rne(acc[rt][nt][reg] + bv);
            }
        }
    }
}

// fc2: D[p][r] = W2 * act(h1)^T; out = D + b2 + x.
__global__ __launch_bounds__(256, 2)
void fc2_kernel(const unsigned short* __restrict__ h1t,
                const unsigned short* __restrict__ w2p,
                const float* __restrict__ b2,
                const float* __restrict__ x,
                float* __restrict__ out) {
    __shared__ __align__(16) unsigned short frag[2 * FB_];
    int blk = blockIdx.x;
    int tid = threadIdx.x;
    int rbase = blk * RT_;

    int colA = tid & 63, scA = tid >> 6;
    int colB = 64 + (tid & 31), scB = tid >> 5;
    int pbase_rbfA  = ((colA >> 5) << 9) + (colA & 31) * 8;
    int pbase_rbfB  = 1024 + (colB & 31) * 8;
    int pbase_siluA = 8 * TS_ + ((colA >> 5) << 9) + ((scA >> 1) << 8) + (colA & 31) * 8 + (scA & 1) * 4;
    int pbase_siluB = 8 * TS_ + 1024 + ((scB >> 2) << 8) + (colB & 31) * 8 + (scB & 3) * 2;

    int wave = tid >> 6, lane = tid & 63;
    int l31 = lane & 31, half = lane >> 5;
    int nt0 = wave * 2;
    int ntn = (wave < 3) ? 2 : 1;
    int off1 = (ntn > 1) ? 64 : 0;           // wave 3 dups its tile (discarded)

    f32x16 acc[3][2];   // [rt][nt]
#pragma unroll
    for (int rt = 0; rt < 3; rt++)
#pragma unroll
        for (int nt = 0; nt < 2; nt++)
#pragma unroll
            for (int i = 0; i < 16; i++) acc[rt][nt][i] = 0.f;

    const short8* wp = (const short8*)w2p;
    short8 wbuf[2][2];

    auto wload = [&](int d, const short8* wt0, int kk) {
        const short8* wt = wt0 + (size_t)kk * (NT2 * 64);
        wbuf[d][0] = wt[0]; wbuf[d][1] = wt[off1];
    };
    auto do_mfma = [&](short8 w0, short8 w1, short8 a0, short8 a1, short8 a2) {
        acc[0][0] = MFMA(w0, a0, acc[0][0]); acc[1][0] = MFMA(w0, a1, acc[1][0]); acc[2][0] = MFMA(w0, a2, acc[2][0]);
        if (ntn == 2) {
            acc[0][1] = MFMA(w1, a0, acc[0][1]); acc[1][1] = MFMA(w1, a1, acc[1][1]); acc[2][1] = MFMA(w1, a2, acc[2][1]);
        }
    };
    auto produce = [&](int fb, const unsigned short (&ra)[4], const unsigned short (&rb2)[2]) {
        float v0 = bf2f(ra[0]), v1 = bf2f(ra[1]), v2 = bf2f(ra[2]), v3 = bf2f(ra[3]);
        float u0 = bf2f(rb2[0]), u1 = bf2f(rb2[1]);
        float vv[4] = {v0, v1, v2, v3};
#pragma unroll
        for (int i = 0; i < 4; i++) {
            int sl = scA * 4 + i;
            *(short8*)&frag[fb + (sl >> 1) * TS_ + ((sl & 1) << 8) + pbase_rbfA] = rbf8(vv[i]);
        }
        float uu[2] = {u0, u1};
#pragma unroll
        for (int i = 0; i < 2; i++) {
            int sl = scB * 2 + i;
            *(short8*)&frag[fb + (sl >> 1) * TS_ + ((sl & 1) << 8) + pbase_rbfB] = rbf8(uu[i]);
        }
        uint2 sv;
        sv.x = silu2(v0, v1);
        sv.y = silu2(v2, v3);
        *(uint2*)&frag[fb + pbase_siluA] = sv;
        *(unsigned int*)&frag[fb + pbase_siluB] = silu2(u0, u1);
    };
    auto body = [&](int cc, const unsigned short (&rbPA)[4], const unsigned short (&rbPB)[2],
                    unsigned short (&rbLA)[4], unsigned short (&rbLB)[2]) {
        bool doProd = (cc + 1 < NC2);
        const short8* wt0 = wp + ((size_t)(cc * 9) * NT2 + nt0) * 64 + lane;
        wload(0, wt0, 0); wload(1, wt0, 1);
        int fbP = ((cc + 1) & 1) * FB_;
        const unsigned short* fg = &frag[(cc & 1) * FB_];
        short8 a0 = *(const short8*)&fg[lane * 8];
        short8 a1 = *(const short8*)&fg[512 + lane * 8];
        short8 a2 = *(const short8*)&fg[1024 + lane * 8];
#pragma unroll
        for (int kk = 0; kk < 9; kk++) {
            short8 na0, na1, na2;
            if (kk < 8) {
                na0 = *(const short8*)&fg[(kk + 1) * TS_ + lane * 8];
                na1 = *(const short8*)&fg[(kk + 1) * TS_ + 512 + lane * 8];
                na2 = *(const short8*)&fg[(kk + 1) * TS_ + 1024 + lane * 8];
            }
            short8 w0 = wbuf[kk & 1][0], w1 = wbuf[kk & 1][1];
            if (kk < 7) wload(kk & 1, wt0, kk + 2);
            if (kk < 4) {
                if (doProd) {
                    int sl = scA * 4 + kk;
                    *(short8*)&frag[fbP + (sl >> 1) * TS_ + ((sl & 1) << 8) + pbase_rbfA] =
                        rbf8(bf2f(rbPA[kk]));
                }
            } else if (kk == 4) {
                if (doProd) {
#pragma unroll
                    for (int i = 0; i < 2; i++) {
                        int sl = scB * 2 + i;
                        *(short8*)&frag[fbP + (sl >> 1) * TS_ + ((sl & 1) << 8) + pbase_rbfB] =
                            rbf8(bf2f(rbPB[i]));
                    }
                }
            } else if (kk == 5) {
                if (doProd) {
                    uint2 sv;
                    sv.x = silu2(bf2f(rbPA[0]), bf2f(rbPA[1]));
                    sv.y = silu2(bf2f(rbPA[2]), bf2f(rbPA[3]));
                    *(uint2*)&frag[fbP + pbase_siluA] = sv;
                    *(unsigned int*)&frag[fbP + pbase_siluB] = silu2(bf2f(rbPB[0]), bf2f(rbPB[1]));
                }
            } else if (kk == 6) {
#pragma unroll
                for (int i = 0; i < 2; i++) {
                    int s = (cc + 2) * 16 + scA * 4 + i;
                    s = (s < HS_) ? s : (HS_ - 1);
                    rbLA[i] = h1t[(size_t)s * M_ + rbase + colA];
                }
            } else if (kk == 7) {
#pragma unroll
                for (int i = 2; i < 4; i++) {
                    int s = (cc + 2) * 16 + scA * 4 + i;
                    s = (s < HS_) ? s : (HS_ - 1);
                    rbLA[i] = h1t[(size_t)s * M_ + rbase + colA];
                }
            } else {
#pragma unroll
                for (int i = 0; i < 2; i++) {
                    int s = (cc + 2) * 16 + scB * 2 + i;
                    s = (s < HS_) ? s : (HS_ - 1);
                    rbLB[i] = h1t[(size_t)s * M_ + rbase + colB];
                }
            }
            do_mfma(w0, w1, a0, a1, a2);
            if (kk < 8) { a0 = na0; a1 = na1; a2 = na2; }
        }
        block_sync_lds();
    };

    unsigned short rbA_A[4], rbB_A[4], rbA_B[2], rbB_B[2];
#pragma unroll
    for (int i = 0; i < 4; i++) {
        rbA_A[i] = h1t[(size_t)(scA * 4 + i) * M_ + rbase + colA];
        rbB_A[i] = h1t[(size_t)(16 + scA * 4 + i) * M_ + rbase + colA];
    }
#pragma unroll
    for (int i = 0; i < 2; i++) {
        rbA_B[i] = h1t[(size_t)(scB * 2 + i) * M_ + rbase + colB];
        rbB_B[i] = h1t[(size_t)(16 + scB * 2 + i) * M_ + rbase + colB];
    }
    produce(0, rbA_A, rbA_B);   // chunk 0 -> frag[0]
    block_sync_lds();

    for (int c2 = 0; c2 < 12; c2++) {        // chunks 0..23
        body(2 * c2,     rbB_A, rbB_B, rbA_A, rbA_B);
        body(2 * c2 + 1, rbA_A, rbA_B, rbB_A, rbB_B);
    }

    // epilogue: out[b,p,c] = acc + b2[p] + x[b,p,c]
    int b = blk >> 3;
    int c0 = (blk & 7) * RT_;
#pragma unroll
    for (int nt = 0; nt < 2; nt++) {
        if (nt < ntn) {
            int p0 = (nt0 + nt) * 32 + 4 * half;
#pragma unroll
            for (int reg = 0; reg < 16; reg++) {
                int p = p0 + (reg & 3) + 8 * (reg >> 2);
                if (p < P_) {
                    float bv = b2[p];
#pragma unroll
                    for (int rt = 0; rt < 3; rt++) {
                        size_t off = ((size_t)b * P_ + p) * C_ + c0 + rt * 32 + l31;
                        out[off] = acc[rt][nt][reg] + bv + x[off];
                    }
                }
            }
        }
    }
}

extern "C" void kernel_launch(void* const* d_in, const int* in_sizes, int n_in,
                              void* d_out, int out_size, void* d_ws, size_t ws_size,
                              hipStream_t stream) {
    const float* x   = (const float*)d_in[0];
    const float* w1s = (const float*)d_in[1];
    const float* w1b = (const float*)d_in[2];
    const float* b1  = (const float*)d_in[3];
    const float* w2s = (const float*)d_in[4];
    const float* w2b = (const float*)d_in[5];
    const float* b2  = (const float*)d_in[6];
    float* out = (float*)d_out;

    unsigned short* h1t = (unsigned short*)d_ws;            // 37.75 MB bf16 [n][r]
    unsigned short* w1p = h1t + H1_ELEMS;
    unsigned short* w2p = w1p + W1P_ELEMS;                  // total ~40.7 MB

    int pack_blocks = (int)((W1P_ELEMS + W2P_ELEMS) / 256);
    pack_w_kernel<<<pack_blocks, 256, 0, stream>>>(w1s, w1b, w2s, w2b, w1p, w2p);
    fc1_kernel<<<NB_, 256, 0, stream>>>(x, w1p, b1, h1t);
    fc2_kernel<<<NB_, 256, 0, stream>>>(h1t, w2p, b2, x, out);
}